// Round 1
// 607.622 us; speedup vs baseline: 1.1711x; 1.1711x over previous
//
#include <hip/hip_runtime.h>

typedef unsigned int uint_t;

// ---------------- compile-time PGA G(3,0,1) tables ----------------
constexpr int MASK_OF_IDX[16] = {0,1,2,4,8,3,5,9,6,10,12,7,11,13,14,15};
constexpr int IDX_OF_MASK[16] = {0,1,2,5,3,6,8,11,4,7,9,12,10,13,14,15};

constexpr int popc4(int v){ int c=0; for(int b=0;b<4;++b) c += (v>>b)&1; return c; }
constexpr int reorder_sign(int a,int b){ int s=0; for(int j=0;j<4;++j) if((b>>j)&1) s += popc4(a>>(j+1)); return (s&1)?-1:1; }
constexpr int dsign_mask(int m){ int comp=(~m)&15; int s=0; for(int j=0;j<4;++j) if((comp>>j)&1) s += popc4(m>>(j+1)); return (s&1)?-1:1; }

struct Tab { int n; int e[256]; };
constexpr Tab build_gp(){
  Tab t{}; t.n=0;
  for(int i=0;i<16;++i) for(int j=0;j<16;++j){
    int a=MASK_OF_IDX[i], b=MASK_OF_IDX[j];
    if(a&b&1) continue;                      // e0^2 = 0
    int k=IDX_OF_MASK[a^b];
    int s=reorder_sign(a,b);
    t.e[t.n++] = i | (j<<4) | (k<<8) | ((s<0)?(1<<12):0);
  }
  return t;
}
constexpr Tab build_jc(){
  Tab t{}; t.n=0;
  for(int i=0;i<16;++i) for(int j=0;j<16;++j){
    int a=MASK_OF_IDX[i], b=MASK_OF_IDX[j];
    int da=(~a)&15, db=(~b)&15;
    if(da&db) continue;
    int m=da|db, km=(~m)&15;
    int k=IDX_OF_MASK[km];
    int s=reorder_sign(da,db)*dsign_mask(a)*dsign_mask(b)*dsign_mask(km);
    t.e[t.n++] = i | (j<<4) | (k<<8) | ((s<0)?(1<<12):0);
  }
  return t;
}
constexpr Tab GPT = build_gp();
constexpr Tab JCT = build_jc();
static_assert(GPT.n==192, "gp nnz");
static_assert(JCT.n==81,  "jc nnz");

// 16 fp32 -> GLOBAL (16B-aligned)
__device__ __forceinline__ void st16(float* p, const float* v){
  float4* q = (float4*)p;
  q[0] = make_float4(v[0],v[1],v[2],v[3]);
  q[1] = make_float4(v[4],v[5],v[6],v[7]);
  q[2] = make_float4(v[8],v[9],v[10],v[11]);
  q[3] = make_float4(v[12],v[13],v[14],v[15]);
}

// one equi_linear accumulation step; weights come as 3 aligned float4 (12 floats, 9 used)
__device__ __forceinline__ void eqstepv(float* acc, const float* xv, const float4* w4){
  float w[12];
  *reinterpret_cast<float4*>(w+0) = w4[0];
  *reinterpret_cast<float4*>(w+4) = w4[1];
  *reinterpret_cast<float4*>(w+8) = w4[2];
  constexpr int G[16] = {0,1,1,1,1,2,2,2,2,2,2,3,3,3,3,4};
#pragma unroll
  for (int k=0;k<16;++k) acc[k] += w[G[k]]*xv[k];
  acc[1]  += w[5]*xv[0];
  acc[5]  += w[6]*xv[2];
  acc[6]  += w[6]*xv[3];
  acc[7]  += w[6]*xv[4];
  acc[11] += w[7]*xv[8];
  acc[12] += w[7]*xv[9];
  acc[13] += w[7]*xv[10];
  acc[15] += w[8]*xv[14];
}

#define TT   16
#define NTHR 256
#define WP1_FLOATS (32*16*48)   // 24576 : [i][c][q*12+k], 9->12 padded
#define WP3_FLOATS (32*16*24)   // 12288 : [cin][g][h*12+k]

// ---- prologue: repack weights into padded, float4-aligned records in workspace ----
__global__ void gatr_pack_w(const float* __restrict__ wbil,
                            const float* __restrict__ wout,
                            float* __restrict__ wp){
  int tid = blockIdx.x*blockDim.x + threadIdx.x;
  if (tid < WP1_FLOATS){
    int k = tid % 12, q = (tid/12)&3, c = (tid/48)&15, i = tid/768;
    wp[tid] = (k<9) ? wbil[(((q<<4)+c)*32 + i)*9 + k] : 0.f;
  } else if (tid < WP1_FLOATS + WP3_FLOATS){
    int u = tid - WP1_FLOATS;
    int k = u % 12, h = (u/12)&1, g = (u/24)&15, ci = u/384;
    wp[tid] = (k<9) ? wout[(((h<<4)+g)*32 + ci)*9 + k] : 0.f;
  }
}

__global__ __launch_bounds__(NTHR, 4) void gatr_fused_kernel(
    const float* __restrict__ xg, const float* __restrict__ refg,
    const float* __restrict__ wp, const float* __restrict__ bbilg,
    const float* __restrict__ boutg, float* __restrict__ outg)
{
  // 32 KiB LDS, time-shared: phase 1 = x tile [16 tok][128 f4, slot-rotated],
  // then (after barrier) Y = [32 ch][16 tok][4 f4, slot-rotated]
  __shared__ float4 LB[2048];

  const int tid = threadIdx.x;
  const size_t tok0 = (size_t)blockIdx.x * TT;

  // ---- stage x tile, coalesced; token tau, logical f4 slot s -> physical (s+tau)&127 ----
  {
    const float4* xg4 = reinterpret_cast<const float4*>(xg + tok0*512);
#pragma unroll
    for (int j=0;j<8;++j){
      int g = tid + j*NTHR;                 // 0..2047
      int tau = g >> 7, f4 = g & 127;
      LB[(tau<<7) + ((f4 + tau) & 127)] = xg4[g];
    }
  }
  __syncthreads();

  const int t = tid & (TT-1);      // token in tile
  const int c = tid >> 4;          // intermediate channel 0..15
  const int rbase = t + (t>>2);    // row-rotation seed

  float gp[16], jn[16];
  // ---- phase 1+2: equi_linear(bilinear) + GP/JC, all in registers ----
  {
    float A0[16], A1[16], A2[16], A3[16];
#pragma unroll
    for (int k=0;k<16;++k){ A0[k]=0.f; A1[k]=0.f; A2[k]=0.f; A3[k]=0.f; }

    const float4* w4 = reinterpret_cast<const float4*>(wp) + c*12;  // record (i=0,c)
    const int tbase = t << 7;
    for (int i=0;i<32;++i){
      float xv[16];
      const int o = (i<<2) + t;
      *reinterpret_cast<float4*>(xv+ 0) = LB[tbase + ( o      & 127)];
      *reinterpret_cast<float4*>(xv+ 4) = LB[tbase + ((o + 1) & 127)];
      *reinterpret_cast<float4*>(xv+ 8) = LB[tbase + ((o + 2) & 127)];
      *reinterpret_cast<float4*>(xv+12) = LB[tbase + ((o + 3) & 127)];
      eqstepv(A0, xv, w4 + 0);
      eqstepv(A1, xv, w4 + 3);
      eqstepv(A2, xv, w4 + 6);
      eqstepv(A3, xv, w4 + 9);
      w4 += 192;                            // next i: 16*48/4
    }
    A0[0] += bbilg[c];
    A1[0] += bbilg[c + 16];
    A2[0] += bbilg[c + 32];
    A3[0] += bbilg[c + 48];

#pragma unroll
    for (int k=0;k<16;++k){ gp[k]=0.f; jn[k]=0.f; }
#pragma unroll
    for (int e=0;e<192;++e){
      const int p = GPT.e[e];
      float v = A0[p & 15] * A1[(p >> 4) & 15];
      if (p & (1<<12)) gp[(p >> 8) & 15] -= v; else gp[(p >> 8) & 15] += v;
    }
#pragma unroll
    for (int e=0;e<81;++e){
      const int p = JCT.e[e];
      float v = A2[p & 15] * A3[(p >> 4) & 15];
      if (p & (1<<12)) jn[(p >> 8) & 15] -= v; else jn[(p >> 8) & 15] += v;
    }
    const float refv = refg[(tok0 + t)*16 + 15];
#pragma unroll
    for (int k=0;k<16;++k) jn[k] *= refv;
  }
  __syncthreads();   // all x reads done -> LB becomes Y

  // ---- write Y rows c (gp) and c+16 (jn); slot rotation (r + ch + t + (t>>2)) & 3 ----
  {
    const int rot = (c + rbase) & 3;       // rows c and c+16 share rot (16 == 0 mod 4)
    const int r0 = (((c     )<<4) + t) << 2;
    const int r1 = (((c + 16)<<4) + t) << 2;
#pragma unroll
    for (int r=0;r<4;++r){
      const int s = (r + rot) & 3;
      LB[r0 + s] = make_float4(gp[4*r], gp[4*r+1], gp[4*r+2], gp[4*r+3]);
      LB[r1 + s] = make_float4(jn[4*r], jn[4*r+1], jn[4*r+2], jn[4*r+3]);
    }
  }
  __syncthreads();

  // ---- phase 3: equi_linear(out) ----
  {
    const int g = c;
    float B0a[16], B1a[16];
#pragma unroll
    for (int k=0;k<16;++k){ B0a[k]=0.f; B1a[k]=0.f; }

    const float4* w6 = reinterpret_cast<const float4*>(wp + WP1_FLOATS) + g*6;
    for (int cin=0; cin<32; ++cin){
      float yv[16];
      const int rowb = ((cin<<4) + t) << 2;
      const int rot  = (cin + rbase) & 3;
#pragma unroll
      for (int r=0;r<4;++r)
        *reinterpret_cast<float4*>(yv + 4*r) = LB[rowb + ((r + rot) & 3)];
      eqstepv(B0a, yv, w6 + 0);
      eqstepv(B1a, yv, w6 + 3);
      w6 += 96;                             // next cin: 16*24/4
    }
    B0a[0] += boutg[g];
    B1a[0] += boutg[g + 16];

    float* orow = outg + (tok0 + t)*512;
    st16(orow + (g     )*16, B0a);
    st16(orow + (g + 16)*16, B1a);
  }
}

extern "C" void kernel_launch(void* const* d_in, const int* in_sizes, int n_in,
                              void* d_out, int out_size, void* d_ws, size_t ws_size,
                              hipStream_t stream) {
  const float* x    = (const float*)d_in[0];
  const float* ref  = (const float*)d_in[1];
  const float* wbil = (const float*)d_in[2];
  const float* bbil = (const float*)d_in[3];
  const float* wout = (const float*)d_in[4];
  const float* bout = (const float*)d_in[5];
  float* out = (float*)d_out;
  float* wp  = (float*)d_ws;               // needs 147456 B of workspace

  hipLaunchKernelGGL(gatr_pack_w,
                     dim3((WP1_FLOATS + WP3_FLOATS + 255)/256), dim3(256), 0, stream,
                     wbil, wout, wp);

  const int ntok = in_sizes[0] / 512;      // 8*8192 = 65536 tokens
  const int grid = ntok / TT;              // 4096 workgroups
  hipLaunchKernelGGL(gatr_fused_kernel, dim3(grid), dim3(NTHR), 0, stream,
                     x, ref, wp, bbil, bout, out);
}

// Round 3
// 427.856 us; speedup vs baseline: 1.6631x; 1.4202x over previous
//
#include <hip/hip_runtime.h>

typedef unsigned int uint_t;

// ---------------- compile-time PGA G(3,0,1) tables ----------------
constexpr int MASK_OF_IDX[16] = {0,1,2,4,8,3,5,9,6,10,12,7,11,13,14,15};
constexpr int IDX_OF_MASK[16] = {0,1,2,5,3,6,8,11,4,7,9,12,10,13,14,15};

constexpr int popc4(int v){ int c=0; for(int b=0;b<4;++b) c += (v>>b)&1; return c; }
constexpr int reorder_sign(int a,int b){ int s=0; for(int j=0;j<4;++j) if((b>>j)&1) s += popc4(a>>(j+1)); return (s&1)?-1:1; }
constexpr int dsign_mask(int m){ int comp=(~m)&15; int s=0; for(int j=0;j<4;++j) if((comp>>j)&1) s += popc4(m>>(j+1)); return (s&1)?-1:1; }

struct Tab { int n; int e[256]; };
constexpr Tab build_gp(){
  Tab t{}; t.n=0;
  for(int i=0;i<16;++i) for(int j=0;j<16;++j){
    int a=MASK_OF_IDX[i], b=MASK_OF_IDX[j];
    if(a&b&1) continue;                      // e0^2 = 0
    int k=IDX_OF_MASK[a^b];
    int s=reorder_sign(a,b);
    t.e[t.n++] = i | (j<<4) | (k<<8) | ((s<0)?(1<<12):0);
  }
  return t;
}
constexpr Tab build_jc(){
  Tab t{}; t.n=0;
  for(int i=0;i<16;++i) for(int j=0;j<16;++j){
    int a=MASK_OF_IDX[i], b=MASK_OF_IDX[j];
    int da=(~a)&15, db=(~b)&15;
    if(da&db) continue;
    int m=da|db, km=(~m)&15;
    int k=IDX_OF_MASK[km];
    int s=reorder_sign(da,db)*dsign_mask(a)*dsign_mask(b)*dsign_mask(km);
    t.e[t.n++] = i | (j<<4) | (k<<8) | ((s<0)?(1<<12):0);
  }
  return t;
}
constexpr Tab GPT = build_gp();
constexpr Tab JCT = build_jc();
static_assert(GPT.n==192, "gp nnz");
static_assert(JCT.n==81,  "jc nnz");

// one equi_linear accumulation step; weights: 3 aligned float4 (12 floats, 9 used).
// With a wave-uniform weight pointer these loads lower to s_load (SGPR broadcast).
__device__ __forceinline__ void eqstepv(float* acc, const float* xv, const float4* w4){
  float w[12];
  *reinterpret_cast<float4*>(w+0) = w4[0];
  *reinterpret_cast<float4*>(w+4) = w4[1];
  *reinterpret_cast<float4*>(w+8) = w4[2];
  constexpr int G[16] = {0,1,1,1,1,2,2,2,2,2,2,3,3,3,3,4};
#pragma unroll
  for (int k=0;k<16;++k) acc[k] += w[G[k]]*xv[k];
  acc[1]  += w[5]*xv[0];
  acc[5]  += w[6]*xv[2];
  acc[6]  += w[6]*xv[3];
  acc[7]  += w[6]*xv[4];
  acc[11] += w[7]*xv[8];
  acc[12] += w[7]*xv[9];
  acc[13] += w[7]*xv[10];
  acc[15] += w[8]*xv[14];
}

#define TT   64      // tokens per workgroup (= lanes per wave)
#define NTHR 1024    // 16 waves; wave w owns channel c = w (wave-uniform)
#define WP1_FLOATS (32*16*48)   // 24576 : [i][c][q*12+k], 9->12 padded
#define WP3_FLOATS (32*16*24)   // 12288 : [cin][g][h*12+k]

// ---- prologue: repack weights into padded, float4-aligned records in workspace ----
__global__ void gatr_pack_w(const float* __restrict__ wbil,
                            const float* __restrict__ wout,
                            float* __restrict__ wp){
  int tid = blockIdx.x*blockDim.x + threadIdx.x;
  if (tid < WP1_FLOATS){
    int k = tid % 12, q = (tid/12)&3, c = (tid/48)&15, i = tid/768;
    wp[tid] = (k<9) ? wbil[(((q<<4)+c)*32 + i)*9 + k] : 0.f;
  } else if (tid < WP1_FLOATS + WP3_FLOATS){
    int u = tid - WP1_FLOATS;
    int k = u % 12, h = (u/12)&1, g = (u/24)&15, ci = u/384;
    wp[tid] = (k<9) ? wout[(((h<<4)+g)*32 + ci)*9 + k] : 0.f;
  }
}

__global__ __launch_bounds__(NTHR, 4) void gatr_fused_kernel(
    const float* __restrict__ xg, const float* __restrict__ refg,
    const float* __restrict__ wp, const float* __restrict__ bbilg,
    const float* __restrict__ boutg, float* __restrict__ outg)
{
  // 128 KiB LDS, time-shared across three phases:
  //   x tile  [64 tok][128 f4]   -> Y tile [64 tok][32ch*4 f4] -> out tile (same as Y)
  // all with physical slot = (logical_f4 + token) & 127  (even bank-group spread;
  // this exact pattern measured SQ_LDS_BANK_CONFLICT == 0 in round 1)
  __shared__ float4 LB[TT * 128];

  const int tid = threadIdx.x;
  const size_t tok0 = (size_t)blockIdx.x * TT;
  const int t = tid & 63;                                   // token lane
  const int c = __builtin_amdgcn_readfirstlane(tid >> 6);   // wave-uniform channel

  // independent prologue load (hides under staging)
  const float refv = refg[(tok0 + t)*16 + 15];

  // ---- stage x tile, coalesced ----
  {
    const float4* xg4 = reinterpret_cast<const float4*>(xg + tok0*512);
#pragma unroll
    for (int j=0;j<8;++j){
      int g = tid + j*NTHR;                 // 0..8191
      int tau = g >> 7, f4 = g & 127;
      LB[(tau<<7) + ((f4 + tau) & 127)] = xg4[g];
    }
  }
  __syncthreads();

  const int tbase = t << 7;

  float gp[16], jn[16];
  // ---- phase 1+2: equi_linear(bilinear) + GP/JC, weights via SGPR broadcast ----
  {
    float A0[16], A1[16], A2[16], A3[16];
#pragma unroll
    for (int k=0;k<16;++k){ A0[k]=0.f; A1[k]=0.f; A2[k]=0.f; A3[k]=0.f; }

    const float4* w4 = reinterpret_cast<const float4*>(wp) + c*12;  // record (i=0,c)
    for (int i=0;i<32;++i){
      float xv[16];
      const int o = (i<<2) + t;
      *reinterpret_cast<float4*>(xv+ 0) = LB[tbase + ( o      & 127)];
      *reinterpret_cast<float4*>(xv+ 4) = LB[tbase + ((o + 1) & 127)];
      *reinterpret_cast<float4*>(xv+ 8) = LB[tbase + ((o + 2) & 127)];
      *reinterpret_cast<float4*>(xv+12) = LB[tbase + ((o + 3) & 127)];
      eqstepv(A0, xv, w4 + 0);
      eqstepv(A1, xv, w4 + 3);
      eqstepv(A2, xv, w4 + 6);
      eqstepv(A3, xv, w4 + 9);
      w4 += 192;                            // next i: 16*48/4
    }
    A0[0] += bbilg[c];
    A1[0] += bbilg[c + 16];
    A2[0] += bbilg[c + 32];
    A3[0] += bbilg[c + 48];

#pragma unroll
    for (int k=0;k<16;++k){ gp[k]=0.f; jn[k]=0.f; }
#pragma unroll
    for (int e=0;e<192;++e){
      const int p = GPT.e[e];
      float v = A0[p & 15] * A1[(p >> 4) & 15];
      if (p & (1<<12)) gp[(p >> 8) & 15] -= v; else gp[(p >> 8) & 15] += v;
    }
#pragma unroll
    for (int e=0;e<81;++e){
      const int p = JCT.e[e];
      float v = A2[p & 15] * A3[(p >> 4) & 15];
      if (p & (1<<12)) jn[(p >> 8) & 15] -= v; else jn[(p >> 8) & 15] += v;
    }
#pragma unroll
    for (int k=0;k<16;++k) jn[k] *= refv;
  }
  __syncthreads();   // all x reads done -> LB becomes Y

  // ---- write Y rows: token t, logical f4 slots [ch*4 + r], same rotation ----
  {
#pragma unroll
    for (int r=0;r<4;++r){
      LB[tbase + (((c     )*4 + r + t) & 127)] = make_float4(gp[4*r], gp[4*r+1], gp[4*r+2], gp[4*r+3]);
      LB[tbase + (((c + 16)*4 + r + t) & 127)] = make_float4(jn[4*r], jn[4*r+1], jn[4*r+2], jn[4*r+3]);
    }
  }
  __syncthreads();

  // ---- phase 3: equi_linear(out), weights via SGPR broadcast ----
  float B0a[16], B1a[16];
  {
#pragma unroll
    for (int k=0;k<16;++k){ B0a[k]=0.f; B1a[k]=0.f; }

    const float4* w6 = reinterpret_cast<const float4*>(wp + WP1_FLOATS) + c*6;
    for (int cin=0; cin<32; ++cin){
      float yv[16];
      const int o = (cin<<2) + t;
      *reinterpret_cast<float4*>(yv+ 0) = LB[tbase + ( o      & 127)];
      *reinterpret_cast<float4*>(yv+ 4) = LB[tbase + ((o + 1) & 127)];
      *reinterpret_cast<float4*>(yv+ 8) = LB[tbase + ((o + 2) & 127)];
      *reinterpret_cast<float4*>(yv+12) = LB[tbase + ((o + 3) & 127)];
      eqstepv(B0a, yv, w6 + 0);
      eqstepv(B1a, yv, w6 + 3);
      w6 += 96;                             // next cin: 16*24/4
    }
    B0a[0] += boutg[c];
    B1a[0] += boutg[c + 16];
  }
  __syncthreads();   // all Y reads done -> LB becomes out tile

  // ---- stage out tile in LDS (same layout/rotation as Y), then coalesced store ----
  {
#pragma unroll
    for (int r=0;r<4;++r){
      LB[tbase + (((c     )*4 + r + t) & 127)] = make_float4(B0a[4*r], B0a[4*r+1], B0a[4*r+2], B0a[4*r+3]);
      LB[tbase + (((c + 16)*4 + r + t) & 127)] = make_float4(B1a[4*r], B1a[4*r+1], B1a[4*r+2], B1a[4*r+3]);
    }
  }
  __syncthreads();
  {
    float4* og4 = reinterpret_cast<float4*>(outg + tok0*512);
#pragma unroll
    for (int j=0;j<8;++j){
      int g = tid + j*NTHR;
      int tau = g >> 7, f4 = g & 127;
      og4[g] = LB[(tau<<7) + ((f4 + tau) & 127)];
    }
  }
}

extern "C" void kernel_launch(void* const* d_in, const int* in_sizes, int n_in,
                              void* d_out, int out_size, void* d_ws, size_t ws_size,
                              hipStream_t stream) {
  const float* x    = (const float*)d_in[0];
  const float* ref  = (const float*)d_in[1];
  const float* wbil = (const float*)d_in[2];
  const float* bbil = (const float*)d_in[3];
  const float* wout = (const float*)d_in[4];
  const float* bout = (const float*)d_in[5];
  float* out = (float*)d_out;
  float* wp  = (float*)d_ws;               // needs 147456 B of workspace

  hipLaunchKernelGGL(gatr_pack_w,
                     dim3((WP1_FLOATS + WP3_FLOATS + 255)/256), dim3(256), 0, stream,
                     wbil, wout, wp);

  const int ntok = in_sizes[0] / 512;      // 8*8192 = 65536 tokens
  const int grid = ntok / TT;              // 1024 workgroups
  hipLaunchKernelGGL(gatr_fused_kernel, dim3(grid), dim3(NTHR), 0, stream,
                     x, ref, wp, bbil, bout, out);
}